// Round 15
// baseline (111.989 us; speedup 1.0000x reference)
//
#include <hip/hip_runtime.h>
#include <hip/hip_bf16.h>

// Problem constants
constexpr int BB  = 4;     // batch
constexpr int CC  = 256;   // channels
constexpr int CQ  = 64;    // q/k channels
constexpr int NN  = 4096;  // H*W
constexpr int KS  = 4;     // key-split factor
constexpr int QTR = 256;   // q-rows per block (8 waves: 4 rowgrp x 2 chgrp)
constexpr int KVB = 64;    // keys per LDS tile (double-buffered)

typedef __attribute__((ext_vector_type(8))) short bf16x8;  // 8 bf16 (4 VGPRs)
typedef __attribute__((ext_vector_type(4))) float f32x4;   // MFMA accumulator

__device__ __forceinline__ short f2bf(float f) {
    unsigned u = __float_as_uint(f);
    unsigned r = u + 0x7fffu + ((u >> 16) & 1u);   // round-to-nearest-even
    return (short)(r >> 16);
}

// native RNE convert (compiler may fuse pairs into v_cvt_pk_bf16_f32)
__device__ __forceinline__ short f2bf_fast(float f) {
    __bf16 h = (__bf16)f;
    return *reinterpret_cast<short*>(&h);
}

// async global->LDS, 16B per lane; LDS dest = wave-uniform base + lane*16
__device__ __forceinline__ void gload16(const void* gsrc, void* ldst) {
    __builtin_amdgcn_global_load_lds(
        (const __attribute__((address_space(1))) unsigned int*)gsrc,
        (__attribute__((address_space(3))) unsigned int*)ldst, 16, 0, 0);
}

// ---------------------------------------------------------------------------
// Kernel 1: QKV projection as MFMA GEMM (round-13, proven).
// ---------------------------------------------------------------------------
__global__ __launch_bounds__(256, 3) void proj_kernel(
        const float* __restrict__ x,
        const float* __restrict__ Wq, const float* __restrict__ bq,
        const float* __restrict__ Wk, const float* __restrict__ bk,
        const float* __restrict__ Wv, const float* __restrict__ bv,
        short* __restrict__ Qt, short* __restrict__ Kt,
        short* __restrict__ Vm) {
    const int id  = blockIdx.x;
    const int xcd = id & 7, sub = id >> 3;
    const int b   = xcd >> 1;
    const int og  = sub >> 4;                       // 0..5
    const int ntl = ((xcd & 1) << 4) + (sub & 15);  // 0..31
    const int n0  = ntl * 128;

    const int t    = threadIdx.x;
    const int wv   = t >> 6;
    const int lane = t & 63;
    const int l15  = lane & 15;
    const int g    = lane >> 4;

    __shared__ __align__(16) short Wl[64 * 256];      // 32KB
    __shared__ __align__(16) short Xl[2][128 * 40];   // 2 x 10KB

    const float* Wsrc; const float* bsrc; float scale;
    if (og == 0)      { Wsrc = Wq;                  bsrc = bq;               scale = 1.4426950408889634f; }
    else if (og == 1) { Wsrc = Wk;                  bsrc = bk;               scale = 1.0f; }
    else              { Wsrc = Wv + (og - 2) * 64 * 256; bsrc = bv + (og - 2) * 64; scale = 1.0f; }

    // ---- stage W once: thread t -> oc = t>>2, k-base = (t&3)*64 ----
    {
        const int oc = t >> 2, kb = (t & 3) * 64;
        const float* wr = Wsrc + oc * 256 + kb;
#pragma unroll
        for (int cc = 0; cc < 8; ++cc) {            // 8 chunks of 8 bf16
            bf16x8 wchunk;
#pragma unroll
            for (int e = 0; e < 8; ++e) wchunk[e] = f2bf_fast(wr[cc * 8 + e] * scale);
            const int c = (kb >> 3) + cc;           // global chunk 0..31
            char* dst = (char*)Wl + oc * 512 + ((c * 16) ^ ((oc & 7) << 4));
            *(bf16x8*)dst = wchunk;
        }
    }

    // ---- x staging: thread t -> n = t&127, k-half = (t>>7)*16 ----
    const int xn   = t & 127;
    const int half = t >> 7;
    const float* xb = x + (size_t)b * CC * NN + n0 + xn;
    const int swn  = ((xn & 3) ^ ((xn >> 3) & 3));  // row XOR term

    auto stageX = [&](int kc, int buf) {
        const float* xr = xb + (size_t)(kc * 32 + half * 16) * NN;
        float v[16];
#pragma unroll
        for (int kk = 0; kk < 16; ++kk) v[kk] = xr[(size_t)kk * NN];
#pragma unroll
        for (int cc = 0; cc < 2; ++cc) {
            bf16x8 pk;
#pragma unroll
            for (int e = 0; e < 8; ++e) pk[e] = f2bf_fast(v[cc * 8 + e]);
            const int c = half * 2 + cc;            // chunk 0..3
            char* dst = (char*)&Xl[buf][0] + xn * 80 + ((c ^ swn) << 4);
            *(bf16x8*)dst = pk;
        }
    };

    f32x4 acc[8];
#pragma unroll
    for (int nf = 0; nf < 8; ++nf) acc[nf] = (f32x4){0.f, 0.f, 0.f, 0.f};

    stageX(0, 0);

    const int ocr = wv * 16 + l15;                  // A-frag row (oc within 64)
    for (int kc = 0; kc < 8; ++kc) {
        __syncthreads();
        if (kc < 7) stageX(kc + 1, (kc + 1) & 1);

        // A-frag: W[ocr][kc*32 + g*8 ..+8]
        const char* wsrcl = (const char*)Wl + ocr * 512
                          + (((kc * 4 + g) * 16) ^ ((ocr & 7) << 4));
        bf16x8 af = *(const bf16x8*)wsrcl;

        const char* xbase = (const char*)&Xl[kc & 1][0];
#pragma unroll
        for (int nf = 0; nf < 8; ++nf) {
            const int n = nf * 16 + l15;
            const int swr = ((n & 3) ^ ((n >> 3) & 3));
            bf16x8 bf = *(const bf16x8*)(xbase + n * 80 + ((g ^ swr) << 4));
            acc[nf] = __builtin_amdgcn_mfma_f32_16x16x32_bf16(af, bf, acc[nf], 0, 0, 0);
        }
    }

    // ---- epilogue: + bias, write per-og layout ----
    float bias4[4];
#pragma unroll
    for (int r = 0; r < 4; ++r) bias4[r] = bsrc[wv * 16 + g * 4 + r] * scale;

    if (og < 2) {
        short* base = (og == 0 ? Qt : Kt) + (size_t)b * NN * 64;
#pragma unroll
        for (int nf = 0; nf < 8; ++nf) {
            const int n = n0 + nf * 16 + l15;
            short4 pk;
            pk.x = f2bf_fast(acc[nf][0] + bias4[0]);
            pk.y = f2bf_fast(acc[nf][1] + bias4[1]);
            pk.z = f2bf_fast(acc[nf][2] + bias4[2]);
            pk.w = f2bf_fast(acc[nf][3] + bias4[3]);
            *(short4*)(base + (size_t)n * 64 + wv * 16 + g * 4) = pk;
        }
    } else {
        short* vb = Vm + (size_t)b * CC * NN;
        const int c0 = (og - 2) * 64 + wv * 16 + g * 4;
#pragma unroll
        for (int nf = 0; nf < 8; ++nf) {
            const int n = n0 + nf * 16 + l15;
#pragma unroll
            for (int r = 0; r < 4; ++r)
                vb[(size_t)(c0 + r) * NN + n] = f2bf_fast(acc[nf][r] + bias4[r]);
        }
    }
}

// ---------------------------------------------------------------------------
// Kernel 2: flash attention, 8-wave blocks (4 row-groups x 2 ch-groups):
// each wave owns 64 q-rows x 128 channels -> V-LDS-read per staged byte
// serves 2x the rows (total V read 1.07GB -> 537MB, net LDS traffic -27%).
// KVB=64 halves barrier count; LDS 80KB, grid 256 = 1 block/CU; 8 waves =
// 2 waves/SIMD with ~240 regs (oacc 128 AGPR + ~110 VGPR) -- NOT r12's
// 1-wave/SIMD trap. QK^T duplicated across the cg pair (MFMA pipe has slack).
// Arithmetic identical to r11 (no-max softmax, swapped QK^T, permuted-K per
// 32-key sub-tile: key = kbase + 32h + s(j), s(j)=8*((j&15)>>2)+4*(j>>4)+(j&3)).
// V layout now [ch][64 keys] 128B rows, swizzle (row&7)<<4 == K's -> V reads
// reuse k_off0/k_off1. exp2/pack fused per-jt so S never lives as an array.
// ---------------------------------------------------------------------------
__global__ __launch_bounds__(512, 2) void flash_kernel(
        const short* __restrict__ Qt, const short* __restrict__ Kt,
        const short* __restrict__ Vm,
        short* __restrict__ Opart, float* __restrict__ Lp) {
    const int id  = blockIdx.x;
    const int xcd = id & 7, sub = id >> 3;          // 8 XCDs round-robin
    const int b   = xcd >> 1;                       // batch -> XCD pair
    const int qt  = sub & 15;                       // 16 q-tiles per batch
    const int ks  = ((xcd & 1) << 1) | (sub >> 4);  // 0..3 key-split

    const int wave = threadIdx.x >> 6;              // 0..7
    const int rg   = wave >> 1;                     // row-group 0..3
    const int cg   = wave & 1;                      // ch-group 0..1
    const int lane = threadIdx.x & 63;
    const int l15  = lane & 15;
    const int g    = lane >> 4;

    __shared__ short Kl[2][KVB * 64];   // 64 slots x 64 dims, 128B rows (8KB/buf)
    __shared__ short Vl[2][CC * KVB];   // 256 ch x 64 keys, 128B rows (32KB/buf)

    const short* Qb = Qt + (size_t)b * NN * 64;
    const short* Kb = Kt + (size_t)b * NN * 64;
    const short* Vb = Vm + (size_t)b * CC * NN;

    const int qbase = qt * QTR + rg * 64;

    // Q fragments: 4 row-frags x 2 k-chunks (32 VGPR)
    bf16x8 qf[4][2];
#pragma unroll
    for (int rf = 0; rf < 4; ++rf)
#pragma unroll
        for (int kk = 0; kk < 2; ++kk)
            qf[rf][kk] = *(const bf16x8*)(Qb + (size_t)(qbase + rf * 16 + l15) * 64
                                          + kk * 32 + g * 8);

    float lsum_p[4] = {0.f, 0.f, 0.f, 0.f};

    f32x4 oacc[4][8];                   // 64 rows x 128 ch -> 128 AGPR
#pragma unroll
    for (int rf = 0; rf < 4; ++rf)
#pragma unroll
        for (int chf = 0; chf < 8; ++chf) oacc[rf][chf] = (f32x4){0.f, 0.f, 0.f, 0.f};

    // lane-constant LDS read offsets (128B rows, swz (row&7)<<4; row&7==l15&7)
    const int k_off0 = l15 * 128 + ((g * 16)      ^ ((l15 & 7) << 4));
    const int k_off1 = l15 * 128 + ((64 + g * 16) ^ ((l15 & 7) << 4));

    // staging: 40 x 1KB segs (32 V + 8 K), 5 per wave; seg = 8 rows of 128B;
    // lane covers row seg*8+(lane>>3), chunk lane&7; source pre-XOR'd.
    const int r8   = lane >> 3;
    const int scol = (((lane & 7) ^ r8) << 4);

    auto stage = [&](int buf, int kbase) {
#pragma unroll
        for (int i = 0; i < 5; ++i) {
            const int s = wave * 5 + i;
            if (s < 32) {
                const int row = s * 8 + r8;          // V channel 0..255
                const char* src = (const char*)(Vb + (size_t)row * NN + kbase) + scol;
                gload16(src, (char*)&Vl[buf][0] + s * 1024);
            } else {
                const int ss   = s - 32;             // 0..7
                const int slot = ss * 8 + r8;        // K slot 0..63
                const int h    = slot >> 5, j = slot & 31;
                const int sj   = (((j & 15) >> 2) << 3) + ((j >> 4) << 2) + (j & 3);
                const char* src = (const char*)(Kb + (size_t)(kbase + h * 32 + sj) * 64)
                                + scol;
                gload16(src, (char*)&Kl[buf][0] + ss * 1024);
            }
        }
    };

    const int kt0 = ks * (NN / KS);
    stage(0, kt0);

    for (int it = 0; it < NN / KS / KVB; ++it) {    // 16 iters
        const int cur = it & 1;
        __syncthreads();   // drains prev prefetch (issued a full phase ago) + fence
        if (it < NN / KS / KVB - 1) stage(cur ^ 1, kt0 + (it + 1) * KVB);

        const char* klb = (const char*)&Kl[cur][0];
        const char* vlb = (const char*)&Vl[cur][0] + cg * 16384;

        // ---- S^T = K Q^T + fused exp2/pack: 64 key-slots x 64 qrows ----
        // slot jt*16+4g+r (sub-tile h=jt>>1, local j=(jt&1)*16+4g+r) holds
        // actual key kbase+32h+8g+4(jt&1)+r -> pf[rf][h][4*(jt&1)+r].
        bf16x8 pf[4][2];
#pragma unroll
        for (int jt = 0; jt < 4; ++jt) {
            bf16x8 kf0 = *(const bf16x8*)(klb + jt * 2048 + k_off0);
            bf16x8 kf1 = *(const bf16x8*)(klb + jt * 2048 + k_off1);
            const int h = jt >> 1, e0 = (jt & 1) * 4;
#pragma unroll
            for (int rf = 0; rf < 4; ++rf) {
                f32x4 a = (f32x4){0.f, 0.f, 0.f, 0.f};
                a = __builtin_amdgcn_mfma_f32_16x16x32_bf16(kf0, qf[rf][0], a, 0, 0, 0);
                a = __builtin_amdgcn_mfma_f32_16x16x32_bf16(kf1, qf[rf][1], a, 0, 0, 0);
#pragma unroll
                for (int r = 0; r < 4; ++r) {
                    float p = exp2f(a[r]);
                    lsum_p[rf] += p;
                    pf[rf][h][e0 + r] = f2bf_fast(p);
                }
            }
        }

        // ---- O += P V : 64 rows x 128 ch per wave ----
        __builtin_amdgcn_s_setprio(1);
#pragma unroll
        for (int chf = 0; chf < 8; ++chf) {
            bf16x8 vf0 = *(const bf16x8*)(vlb + chf * 2048 + k_off0);
            bf16x8 vf1 = *(const bf16x8*)(vlb + chf * 2048 + k_off1);
#pragma unroll
            for (int rf = 0; rf < 4; ++rf) {
                oacc[rf][chf] = __builtin_amdgcn_mfma_f32_16x16x32_bf16(pf[rf][0], vf0,
                                                                        oacc[rf][chf], 0, 0, 0);
                oacc[rf][chf] = __builtin_amdgcn_mfma_f32_16x16x32_bf16(pf[rf][1], vf1,
                                                                        oacc[rf][chf], 0, 0, 0);
            }
        }
        __builtin_amdgcn_s_setprio(0);
    }

    // ---- epilogue: unnormalized bf16 partials + lsum (cg==0 writes) ----
    const int pt = (b * 16 + qt) * KS + ks;
    short* Op = Opart + (size_t)pt * QTR * 256;
#pragma unroll
    for (int rf = 0; rf < 4; ++rf)
#pragma unroll
        for (int chf = 0; chf < 8; ++chf)
#pragma unroll
            for (int r = 0; r < 4; ++r)
                Op[(size_t)(rg * 64 + rf * 16 + g * 4 + r) * 256
                   + cg * 128 + chf * 16 + l15] = f2bf_fast(oacc[rf][chf][r]);
    if (cg == 0) {
#pragma unroll
        for (int rf = 0; rf < 4; ++rf) {
            float v = lsum_p[rf];
            v += __shfl_xor(v, 16);
            v += __shfl_xor(v, 32);
            if (lane < 16)
                Lp[(size_t)pt * QTR + rg * 64 + rf * 16 + lane] = v;
        }
    }
}

// ---------------------------------------------------------------------------
// Kernel 3: split-K combine + residual epilogue (QTR=256 partial tiles).
// grid (B, N/32), block 256. 32 q-rows x 256 channels per block.
// ---------------------------------------------------------------------------
__global__ __launch_bounds__(256) void combine_kernel(
        const short* __restrict__ Opart, const float* __restrict__ Lp,
        const float* __restrict__ x, const float* __restrict__ weightp,
        float* __restrict__ out) {
    const int b     = blockIdx.x;
    const int rowg0 = blockIdx.y * 32;             // first global q-row
    const int qt    = rowg0 >> 8;                  // 256-row partial tile
    const int rbase = rowg0 & 255;                 // offset within tile
    const int t     = threadIdx.x;

    __shared__ float oc[32][257];
    __shared__ float linv[32];

    const int pt0 = (b * 16 + qt) * KS;

    if (t < 32) {
        const size_t mb = (size_t)pt0 * QTR + rbase + t;
        float L = 0.f;
#pragma unroll
        for (int s = 0; s < KS; ++s) L += Lp[mb + (size_t)s * QTR];
        linv[t] = 1.0f / L;
    }
    __syncthreads();

    const size_t ob = (size_t)pt0 * QTR * 256 + (size_t)rbase * 256;
    const int cp = t & 127;                        // channel pair: ch 2cp, 2cp+1
    const int rh = t >> 7;                         // row half
#pragma unroll 4
    for (int rr = 0; rr < 16; ++rr) {
        const int row = rh * 16 + rr;
        float a0 = 0.f, a1 = 0.f;
#pragma unroll
        for (int s = 0; s < KS; ++s) {
            unsigned u = *(const unsigned*)
                &Opart[ob + (size_t)s * QTR * 256 + row * 256 + cp * 2];
            a0 += __uint_as_float(u << 16);
            a1 += __uint_as_float(u & 0xffff0000u);
        }
        const float li = linv[row];
        oc[row][cp * 2]     = a0 * li;
        oc[row][cp * 2 + 1] = a1 * li;
    }
    __syncthreads();

    const float wgt = weightp[0];
    const int row = t & 31, cg = t >> 5;           // 8 channel groups
    const float* xb = x + (size_t)b * CC * NN + rowg0 + row;
    float* op = out + (size_t)b * CC * NN + rowg0 + row;
#pragma unroll 4
    for (int c = cg; c < 256; c += 8) {
        op[(size_t)c * NN] = wgt * oc[row][c] + xb[(size_t)c * NN];
    }
}

extern "C" void kernel_launch(void* const* d_in, const int* in_sizes, int n_in,
                              void* d_out, int out_size, void* d_ws, size_t ws_size,
                              hipStream_t stream) {
    const float* feat = (const float*)d_in[0];
    const float* Wq   = (const float*)d_in[1];
    const float* bq   = (const float*)d_in[2];
    const float* Wk   = (const float*)d_in[3];
    const float* bk   = (const float*)d_in[4];
    const float* Wv   = (const float*)d_in[5];
    const float* bv   = (const float*)d_in[6];
    const float* wgt  = (const float*)d_in[7];
    float* out = (float*)d_out;

    short* Qt = (short*)d_ws;                       // [B][N][64] bf16 (log2e-scaled)
    short* Kt = Qt + (size_t)BB * NN * CQ;          // [B][N][64] bf16
    short* Vm = Kt + (size_t)BB * NN * CQ;          // [B][256][N] bf16
    short* Opart = Vm + (size_t)BB * CC * NN;       // [256][256][256] bf16
    float* Lp = (float*)(Opart + (size_t)BB * 16 * KS * QTR * 256);  // [256][256]

    proj_kernel<<<dim3(768), 256, 0, stream>>>(
        feat, Wq, bq, Wk, bk, Wv, bv, Qt, Kt, Vm);

    flash_kernel<<<dim3(BB * 16 * KS), 512, 0, stream>>>(
        Qt, Kt, Vm, Opart, Lp);

    combine_kernel<<<dim3(BB, NN / 32), 256, 0, stream>>>(
        Opart, Lp, feat, wgt, out);
}

// Round 16
// 85.339 us; speedup vs baseline: 1.3123x; 1.3123x over previous
//
#include <hip/hip_runtime.h>
#include <hip/hip_bf16.h>

// Problem constants
constexpr int BB  = 4;     // batch
constexpr int CC  = 256;   // channels
constexpr int CQ  = 64;    // q/k channels
constexpr int NN  = 4096;  // H*W
constexpr int KS  = 4;     // key-split factor
constexpr int QTR = 128;   // q-rows per block (4 waves x 32 rows)
constexpr int KVB = 32;    // keys per LDS tile (double-buffered)

typedef __attribute__((ext_vector_type(8))) short bf16x8;  // 8 bf16 (4 VGPRs)
typedef __attribute__((ext_vector_type(4))) float f32x4;   // MFMA accumulator

__device__ __forceinline__ short f2bf(float f) {
    unsigned u = __float_as_uint(f);
    unsigned r = u + 0x7fffu + ((u >> 16) & 1u);   // round-to-nearest-even
    return (short)(r >> 16);
}

// native RNE convert (compiler may fuse pairs into v_cvt_pk_bf16_f32)
__device__ __forceinline__ short f2bf_fast(float f) {
    __bf16 h = (__bf16)f;
    return *reinterpret_cast<short*>(&h);
}

// async global->LDS, 16B per lane; LDS dest = wave-uniform base + lane*16
__device__ __forceinline__ void gload16(const void* gsrc, void* ldst) {
    __builtin_amdgcn_global_load_lds(
        (const __attribute__((address_space(1))) unsigned int*)gsrc,
        (__attribute__((address_space(3))) unsigned int*)ldst, 16, 0, 0);
}

// ---------------------------------------------------------------------------
// Kernel 1: QKV projection as MFMA GEMM (round-13, proven).
//   Y[384][N] = Wcat[384][256] . x[256][N] + bias, per batch.
// grid 768 = 8 XCDs x 96: b = xcd>>1 (batch pinned to XCD pair -> its x half
// stays L2-resident across og re-reads), og picks Q/K/V row-block.
// ---------------------------------------------------------------------------
__global__ __launch_bounds__(256, 3) void proj_kernel(
        const float* __restrict__ x,
        const float* __restrict__ Wq, const float* __restrict__ bq,
        const float* __restrict__ Wk, const float* __restrict__ bk,
        const float* __restrict__ Wv, const float* __restrict__ bv,
        short* __restrict__ Qt, short* __restrict__ Kt,
        short* __restrict__ Vm) {
    const int id  = blockIdx.x;
    const int xcd = id & 7, sub = id >> 3;
    const int b   = xcd >> 1;
    const int og  = sub >> 4;                       // 0..5
    const int ntl = ((xcd & 1) << 4) + (sub & 15);  // 0..31
    const int n0  = ntl * 128;

    const int t    = threadIdx.x;
    const int wv   = t >> 6;
    const int lane = t & 63;
    const int l15  = lane & 15;
    const int g    = lane >> 4;

    __shared__ __align__(16) short Wl[64 * 256];      // 32KB
    __shared__ __align__(16) short Xl[2][128 * 40];   // 2 x 10KB

    const float* Wsrc; const float* bsrc; float scale;
    if (og == 0)      { Wsrc = Wq;                  bsrc = bq;               scale = 1.4426950408889634f; }
    else if (og == 1) { Wsrc = Wk;                  bsrc = bk;               scale = 1.0f; }
    else              { Wsrc = Wv + (og - 2) * 64 * 256; bsrc = bv + (og - 2) * 64; scale = 1.0f; }

    // ---- stage W once: thread t -> oc = t>>2, k-base = (t&3)*64 ----
    {
        const int oc = t >> 2, kb = (t & 3) * 64;
        const float* wr = Wsrc + oc * 256 + kb;
#pragma unroll
        for (int cc = 0; cc < 8; ++cc) {            // 8 chunks of 8 bf16
            bf16x8 wchunk;
#pragma unroll
            for (int e = 0; e < 8; ++e) wchunk[e] = f2bf_fast(wr[cc * 8 + e] * scale);
            const int c = (kb >> 3) + cc;           // global chunk 0..31
            char* dst = (char*)Wl + oc * 512 + ((c * 16) ^ ((oc & 7) << 4));
            *(bf16x8*)dst = wchunk;
        }
    }

    // ---- x staging: thread t -> n = t&127, k-half = (t>>7)*16 ----
    const int xn   = t & 127;
    const int half = t >> 7;
    const float* xb = x + (size_t)b * CC * NN + n0 + xn;
    const int swn  = ((xn & 3) ^ ((xn >> 3) & 3));  // row XOR term

    auto stageX = [&](int kc, int buf) {
        const float* xr = xb + (size_t)(kc * 32 + half * 16) * NN;
        float v[16];
#pragma unroll
        for (int kk = 0; kk < 16; ++kk) v[kk] = xr[(size_t)kk * NN];
#pragma unroll
        for (int cc = 0; cc < 2; ++cc) {
            bf16x8 pk;
#pragma unroll
            for (int e = 0; e < 8; ++e) pk[e] = f2bf_fast(v[cc * 8 + e]);
            const int c = half * 2 + cc;            // chunk 0..3
            char* dst = (char*)&Xl[buf][0] + xn * 80 + ((c ^ swn) << 4);
            *(bf16x8*)dst = pk;
        }
    };

    f32x4 acc[8];
#pragma unroll
    for (int nf = 0; nf < 8; ++nf) acc[nf] = (f32x4){0.f, 0.f, 0.f, 0.f};

    stageX(0, 0);

    const int ocr = wv * 16 + l15;                  // A-frag row (oc within 64)
    for (int kc = 0; kc < 8; ++kc) {
        __syncthreads();
        if (kc < 7) stageX(kc + 1, (kc + 1) & 1);

        // A-frag: W[ocr][kc*32 + g*8 ..+8]
        const char* wsrcl = (const char*)Wl + ocr * 512
                          + (((kc * 4 + g) * 16) ^ ((ocr & 7) << 4));
        bf16x8 af = *(const bf16x8*)wsrcl;

        const char* xbase = (const char*)&Xl[kc & 1][0];
#pragma unroll
        for (int nf = 0; nf < 8; ++nf) {
            const int n = nf * 16 + l15;
            const int swr = ((n & 3) ^ ((n >> 3) & 3));
            bf16x8 bf = *(const bf16x8*)(xbase + n * 80 + ((g ^ swr) << 4));
            acc[nf] = __builtin_amdgcn_mfma_f32_16x16x32_bf16(af, bf, acc[nf], 0, 0, 0);
        }
    }

    // ---- epilogue: + bias, write per-og layout ----
    float bias4[4];
#pragma unroll
    for (int r = 0; r < 4; ++r) bias4[r] = bsrc[wv * 16 + g * 4 + r] * scale;

    if (og < 2) {
        short* base = (og == 0 ? Qt : Kt) + (size_t)b * NN * 64;
#pragma unroll
        for (int nf = 0; nf < 8; ++nf) {
            const int n = n0 + nf * 16 + l15;
            short4 pk;
            pk.x = f2bf_fast(acc[nf][0] + bias4[0]);
            pk.y = f2bf_fast(acc[nf][1] + bias4[1]);
            pk.z = f2bf_fast(acc[nf][2] + bias4[2]);
            pk.w = f2bf_fast(acc[nf][3] + bias4[3]);
            *(short4*)(base + (size_t)n * 64 + wv * 16 + g * 4) = pk;
        }
    } else {
        short* vb = Vm + (size_t)b * CC * NN;
        const int c0 = (og - 2) * 64 + wv * 16 + g * 4;
#pragma unroll
        for (int nf = 0; nf < 8; ++nf) {
            const int n = n0 + nf * 16 + l15;
#pragma unroll
            for (int r = 0; r < 4; ++r)
                vb[(size_t)(c0 + r) * NN + n] = f2bf_fast(acc[nf][r] + bias4[r]);
        }
    }
}

// ---------------------------------------------------------------------------
// Kernel 2: flash attention — round-11 structure (61.4us, best measured).
// 4 waves x 32 q-rows, KVB=32 dbuf, 2 blocks/CU (decoupled barriers),
// no-max softmax (split-K combine renormalizes), swapped QK^T + permuted-K
// staging -> P lane-local in PV A-fragment layout, zero bank conflicts.
// r12/r15 proved: more rows/wave or 8-wave ch-split breaks the 256-reg
// 2-wave budget (spill) or the 2-block/CU decoupling. This is the optimum.
// ---------------------------------------------------------------------------
__global__ __launch_bounds__(256, 2) void flash_kernel(
        const short* __restrict__ Qt, const short* __restrict__ Kt,
        const short* __restrict__ Vm,
        short* __restrict__ Opart, float* __restrict__ Lp) {
    const int id  = blockIdx.x;
    const int xcd = id & 7, sub = id >> 3;          // 8 XCDs round-robin
    const int b   = xcd >> 1;                       // batch -> XCD pair
    const int qt  = sub & 31;                       // 32 q-tiles per batch
    const int ks  = ((xcd & 1) << 1) | (sub >> 5);  // 0..3 key-split

    const int wave = threadIdx.x >> 6;
    const int lane = threadIdx.x & 63;
    const int l15  = lane & 15;
    const int g    = lane >> 4;

    __shared__ short Kl[2][KVB * 64];     // [key-slot][64 dims], 128B rows, swz (row&7)<<4
    __shared__ short Vl[2][CC * KVB];     // [ch][32 keys], 64B rows, swz ((row>>1)&3)<<4

    const short* Qb = Qt + (size_t)b * NN * 64;
    const short* Kb = Kt + (size_t)b * NN * 64;
    const short* Vb = Vm + (size_t)b * CC * NN;

    const int qbase = qt * QTR + wave * 32;

    bf16x8 qf[2][2];
#pragma unroll
    for (int rf = 0; rf < 2; ++rf)
#pragma unroll
        for (int kk = 0; kk < 2; ++kk)
            qf[rf][kk] = *(const bf16x8*)(Qb + (size_t)(qbase + rf * 16 + l15) * 64
                                          + kk * 32 + g * 8);

    float lsum_p[2] = {0.0f, 0.0f};

    f32x4 oacc[2][16];
#pragma unroll
    for (int rf = 0; rf < 2; ++rf)
#pragma unroll
        for (int ch = 0; ch < 16; ++ch) oacc[rf][ch] = (f32x4){0.f, 0.f, 0.f, 0.f};

    const int vrow_off = lane >> 2;
    const int vscol    = (((lane & 3) ^ ((lane >> 3) & 3)) << 4);
    const int krow_off = lane >> 3;
    const int kscol    = (((lane & 7) ^ (lane >> 3)) << 4);

    auto stage = [&](int buf, int kbase) {
#pragma unroll
        for (int i = 0; i < 5; ++i) {
            const int s = wave * 5 + i;
            if (s < 16) {
                const int row = s * 16 + vrow_off;
                const char* src = (const char*)(Vb + (size_t)row * NN + kbase) + vscol;
                gload16(src, (char*)&Vl[buf][0] + s * 1024);
            } else {
                const int ss = s - 16;
                const int j  = ss * 8 + krow_off;
                const int sj = (((j & 15) >> 2) << 3) + ((j >> 4) << 2) + (j & 3);
                const char* src = (const char*)(Kb + (size_t)(kbase + sj) * 64) + kscol;
                gload16(src, (char*)&Kl[buf][0] + ss * 1024);
            }
        }
    };

    const int kt0 = ks * (NN / KS);
    stage(0, kt0);

    for (int it = 0; it < NN / KS / KVB; ++it) {
        const int cur = it & 1;
        __syncthreads();
        if (it < NN / KS / KVB - 1) stage(cur ^ 1, kt0 + (it + 1) * KVB);

        f32x4 s2[2][2];
#pragma unroll
        for (int jt = 0; jt < 2; ++jt) {
            const int krow = jt * 16 + l15;
            const int sw   = (krow & 7) << 4;
            const char* kr = (const char*)&Kl[cur][0] + krow * 128;
            bf16x8 kf0 = *(const bf16x8*)(kr + ((g * 16) ^ sw));
            bf16x8 kf1 = *(const bf16x8*)(kr + ((64 + g * 16) ^ sw));
#pragma unroll
            for (int rf = 0; rf < 2; ++rf) {
                f32x4 a = (f32x4){0.f, 0.f, 0.f, 0.f};
                a = __builtin_amdgcn_mfma_f32_16x16x32_bf16(kf0, qf[rf][0], a, 0, 0, 0);
                a = __builtin_amdgcn_mfma_f32_16x16x32_bf16(kf1, qf[rf][1], a, 0, 0, 0);
                s2[rf][jt] = a;
            }
        }

        bf16x8 pf[2];
#pragma unroll
        for (int rf = 0; rf < 2; ++rf) {
#pragma unroll
            for (int jt = 0; jt < 2; ++jt)
#pragma unroll
                for (int r = 0; r < 4; ++r) {
                    float p = exp2f(s2[rf][jt][r]);
                    lsum_p[rf] += p;
                    pf[rf][jt * 4 + r] = f2bf_fast(p);
                }
        }

        __builtin_amdgcn_s_setprio(1);
#pragma unroll
        for (int ch = 0; ch < 16; ++ch) {
            const int vrow = ch * 16 + l15;
            const int col  = (g * 16) ^ (((vrow >> 1) & 3) << 4);
            bf16x8 vf = *(const bf16x8*)((const char*)&Vl[cur][0] + vrow * 64 + col);
#pragma unroll
            for (int rf = 0; rf < 2; ++rf)
                oacc[rf][ch] = __builtin_amdgcn_mfma_f32_16x16x32_bf16(pf[rf], vf,
                                                                       oacc[rf][ch], 0, 0, 0);
        }
        __builtin_amdgcn_s_setprio(0);
    }

    const int pt = (b * 32 + qt) * KS + ks;
    short* Op = Opart + (size_t)pt * QTR * 256;
#pragma unroll
    for (int rf = 0; rf < 2; ++rf)
#pragma unroll
        for (int ch = 0; ch < 16; ++ch)
#pragma unroll
            for (int r = 0; r < 4; ++r)
                Op[(size_t)(wave * 32 + rf * 16 + g * 4 + r) * 256 + ch * 16 + l15] =
                    f2bf_fast(oacc[rf][ch][r]);
#pragma unroll
    for (int rf = 0; rf < 2; ++rf) {
        float v = lsum_p[rf];
        v += __shfl_xor(v, 16);
        v += __shfl_xor(v, 32);
        if (lane < 16)
            Lp[(size_t)pt * QTR + wave * 32 + rf * 16 + lane] = v;
    }
}

// ---------------------------------------------------------------------------
// Kernel 3: split-K combine + residual epilogue (round-13, proven).
// ---------------------------------------------------------------------------
__global__ __launch_bounds__(256) void combine_kernel(
        const short* __restrict__ Opart, const float* __restrict__ Lp,
        const float* __restrict__ x, const float* __restrict__ weightp,
        float* __restrict__ out) {
    const int b     = blockIdx.x;
    const int rowg0 = blockIdx.y * 32;             // first global q-row
    const int qt    = rowg0 >> 7;                  // 128-row partial tile
    const int rbase = rowg0 & 127;                 // offset within tile
    const int t     = threadIdx.x;

    __shared__ float oc[32][257];
    __shared__ float linv[32];

    const int pt0 = (b * 32 + qt) * KS;

    if (t < 32) {
        const size_t mb = (size_t)pt0 * QTR + rbase + t;
        float L = 0.f;
#pragma unroll
        for (int s = 0; s < KS; ++s) L += Lp[mb + (size_t)s * QTR];
        linv[t] = 1.0f / L;
    }
    __syncthreads();

    const size_t ob = (size_t)pt0 * QTR * 256 + (size_t)rbase * 256;
#pragma unroll 4
    for (int row = 0; row < 32; ++row) {
        float acc = 0.f;
#pragma unroll
        for (int s = 0; s < KS; ++s) {
            unsigned u = (unsigned)(unsigned short)
                Opart[ob + (size_t)s * QTR * 256 + row * 256 + t];
            acc += __uint_as_float(u << 16);
        }
        oc[row][t] = acc * linv[row];
    }
    __syncthreads();

    const float wgt = weightp[0];
    const int row = t & 31, cg = t >> 5;           // 8 channel groups
    const float* xb = x + (size_t)b * CC * NN + rowg0 + row;
    float* op = out + (size_t)b * CC * NN + rowg0 + row;
#pragma unroll 4
    for (int c = cg; c < 256; c += 8) {
        op[(size_t)c * NN] = wgt * oc[row][c] + xb[(size_t)c * NN];
    }
}

extern "C" void kernel_launch(void* const* d_in, const int* in_sizes, int n_in,
                              void* d_out, int out_size, void* d_ws, size_t ws_size,
                              hipStream_t stream) {
    const float* feat = (const float*)d_in[0];
    const float* Wq   = (const float*)d_in[1];
    const float* bq   = (const float*)d_in[2];
    const float* Wk   = (const float*)d_in[3];
    const float* bk   = (const float*)d_in[4];
    const float* Wv   = (const float*)d_in[5];
    const float* bv   = (const float*)d_in[6];
    const float* wgt  = (const float*)d_in[7];
    float* out = (float*)d_out;

    short* Qt = (short*)d_ws;                       // [B][N][64] bf16 (log2e-scaled)
    short* Kt = Qt + (size_t)BB * NN * CQ;          // [B][N][64] bf16
    short* Vm = Kt + (size_t)BB * NN * CQ;          // [B][256][N] bf16
    short* Opart = Vm + (size_t)BB * CC * NN;       // [512][128][256] bf16
    float* Lp = (float*)(Opart + (size_t)BB * 32 * KS * QTR * 256);  // [512][128]

    proj_kernel<<<dim3(768), 256, 0, stream>>>(
        feat, Wq, bq, Wk, bk, Wv, bv, Qt, Kt, Vm);

    flash_kernel<<<dim3(BB * 32 * KS), 256, 0, stream>>>(
        Qt, Kt, Vm, Opart, Lp);

    combine_kernel<<<dim3(BB, NN / 32), 256, 0, stream>>>(
        Opart, Lp, feat, wgt, out);
}